// Round 3
// baseline (260.643 us; speedup 1.0000x reference)
//
#include <hip/hip_runtime.h>
#include <math.h>

// Problem constants: B=1, H=W=64 (N=4096), C=768, 12 heads x hd=64.
#define NHEADS 12
#define NTOK 4096
#define LOG2E 1.44269504f

typedef __attribute__((ext_vector_type(8))) short bf8v;    // 8 x bf16
typedef __attribute__((ext_vector_type(4))) float f4v;     // 16x16 C/D frag
typedef __attribute__((ext_vector_type(16))) float f16v;   // 32x32 C/D frag

__device__ __forceinline__ unsigned short f2bf(float f) {
  unsigned int u = __float_as_uint(f);
  u += 0x7fffu + ((u >> 16) & 1u);   // RNE
  return (unsigned short)(u >> 16);
}
__device__ __forceinline__ bf8v pack8(float4 a, float4 b) {
  bf8v v;
  v[0] = (short)f2bf(a.x); v[1] = (short)f2bf(a.y);
  v[2] = (short)f2bf(a.z); v[3] = (short)f2bf(a.w);
  v[4] = (short)f2bf(b.x); v[5] = (short)f2bf(b.y);
  v[6] = (short)f2bf(b.z); v[7] = (short)f2bf(b.w);
  return v;
}
// pack two f32 (round via +0x8000) into (hi|lo) bf16 pair
__device__ __forceinline__ unsigned pkbf(float hi, float lo) {
  return __builtin_amdgcn_perm(__float_as_uint(hi) + 0x8000u,
                               __float_as_uint(lo) + 0x8000u, 0x07060302u);
}
// pack two f32 into (hi=b | lo=a) bf16 pair in ONE instruction
__device__ __forceinline__ unsigned cvtpk(float lo, float hi) {
  unsigned r;
  asm("v_cvt_pk_bf16_f32 %0, %1, %2" : "=v"(r) : "v"(lo), "v"(hi));
  return r;
}
__device__ __forceinline__ void gload_lds16(const void* g, void* l) {
  __builtin_amdgcn_global_load_lds(
      (const __attribute__((address_space(1))) void*)g,
      (__attribute__((address_space(3))) void*)l, 16, 0, 0);
}

// ---------------------------------------------------------------------------
// prep: unified x->bf16 cvt + qkv_w / proj_w transpose-cvt (one launch).
// blocks [0,1536): cvt; [1536,1968): tcvt qkvw; [1968,2112): tcvt pw.
// ---------------------------------------------------------------------------
__device__ __forceinline__ void tcvt_body(
    const float* __restrict__ in, short* __restrict__ out, int R, int C,
    int bx, int by, int t, float (*Ts)[65])
{
    const int bc = bx * 64, br = by * 64;
    {
        const int r = t >> 2, c0 = (t & 3) * 16;
        const float* src = in + (size_t)(br + r) * C + bc + c0;
#pragma unroll
        for (int i = 0; i < 4; ++i) {
            float4 a = *(const float4*)(src + 4 * i);
            Ts[r][c0 + 4 * i + 0] = a.x;
            Ts[r][c0 + 4 * i + 1] = a.y;
            Ts[r][c0 + 4 * i + 2] = a.z;
            Ts[r][c0 + 4 * i + 3] = a.w;
        }
    }
    __syncthreads();
    const int c = t >> 2, r0 = (t & 3) * 16;
    short* dst = out + (size_t)(bc + c) * R + br + r0;
#pragma unroll
    for (int p = 0; p < 2; ++p) {
        bf8v v;
#pragma unroll
        for (int i = 0; i < 8; ++i) v[i] = (short)f2bf(Ts[r0 + p * 8 + i][c]);
        *(bf8v*)(dst + p * 8) = v;
    }
}

__global__ __launch_bounds__(256) void prep_kernel(
    const float* __restrict__ x, const float* __restrict__ qkvw,
    const float* __restrict__ pw, short* __restrict__ xh,
    short* __restrict__ wqkvT, short* __restrict__ pwT)
{
    __shared__ float Ts[64][65];
    const int bid = blockIdx.x, t = threadIdx.x;
    if (bid < 1536) {
        const size_t i = ((size_t)bid * 256 + t) * 8;
        float4 a = *(const float4*)(x + i);
        float4 b = *(const float4*)(x + i + 4);
        *(bf8v*)(xh + i) = pack8(a, b);
    } else if (bid < 1968) {
        const int idx = bid - 1536;
        tcvt_body(qkvw, wqkvT, 768, 2304, idx % 36, idx / 36, t, Ts);
    } else {
        const int idx = bid - 1968;
        tcvt_body(pw, pwT, 768, 768, idx % 12, idx / 12, t, Ts);
    }
}

// ---------------------------------------------------------------------------
// QKV GEMM (MFMA bf16): 128x96 tile, grid (24,32)=768 blocks.
// V epilogue writes BLOCKED layout vblk[h][tok/16][d][tok%16].
// K epilogue writes blocked MFMA-A-fragment-order layout
//   kblk[h][tok>>5][d>>3][tok&31][d&7]
// ---------------------------------------------------------------------------
__global__ __launch_bounds__(256) void qkv_mfma_kernel(
    const short* __restrict__ xh, const short* __restrict__ wT,
    const float* __restrict__ bias, short* __restrict__ qbh,
    short* __restrict__ kblk, short* __restrict__ vblk)
{
    __shared__ __align__(16) short As[128 * 32];
    __shared__ __align__(16) short Bs[96 * 32];
    const int t = threadIdx.x;
    const int w = t >> 6, lane = t & 63;
    const int l15 = lane & 15, l4 = lane >> 4;
    const int wr = w >> 1, wc = w & 1;
    const int row0 = blockIdx.y * 128, col0 = blockIdx.x * 96;
    const int ldr = lane >> 2;
    const int ldk = (lane & 3) * 8;

    f4v acc[4][3] = {};
    const short* aBase = xh + (size_t)(row0 + w * 32 + ldr) * 768 + ldk;
    const short* bBase0 = wT + (size_t)(col0 + w * 16 + ldr) * 768 + ldk;
    const short* bBase1 = wT + (size_t)(col0 + 64 + w * 16 + ldr) * 768 + ldk;

    for (int kk = 0; kk < 768; kk += 32) {
        __syncthreads();
#pragma unroll
        for (int c = 0; c < 2; ++c)
            gload_lds16(aBase + (size_t)c * 16 * 768 + kk,
                        &As[(w * 32 + c * 16) * 32]);
        gload_lds16(bBase0 + kk, &Bs[(w * 16) * 32]);
        if (w < 2)   // wave-uniform: waves 0,1 stage B chunks 4,5
            gload_lds16(bBase1 + kk, &Bs[(64 + w * 16) * 32]);
        __syncthreads();
        bf8v af[4], bg[3];
#pragma unroll
        for (int i = 0; i < 4; ++i)
            af[i] = *(const bf8v*)&As[(wr * 64 + 16 * i + l15) * 32 + l4 * 8];
#pragma unroll
        for (int j = 0; j < 3; ++j)
            bg[j] = *(const bf8v*)&Bs[(wc * 48 + 16 * j + l15) * 32 + l4 * 8];
#pragma unroll
        for (int i = 0; i < 4; ++i)
#pragma unroll
            for (int j = 0; j < 3; ++j)
                acc[i][j] = __builtin_amdgcn_mfma_f32_16x16x32_bf16(
                    af[i], bg[j], acc[i][j], 0, 0, 0);
    }

#pragma unroll
    for (int j = 0; j < 3; ++j) {
        const int n = col0 + wc * 48 + 16 * j + l15;
        const int s = n / 768;            // block-uniform (96 | 768)
        const int rm = n - s * 768;
        const int h = rm >> 6, d = rm & 63;
        const float bv = bias[n];
        if (s == 2) {
#pragma unroll
            for (int i = 0; i < 4; ++i) {
                const int m = row0 + wr * 64 + 16 * i + l4 * 4;
                short4 pv;
                pv.x = (short)f2bf(acc[i][j][0] + bv);
                pv.y = (short)f2bf(acc[i][j][1] + bv);
                pv.z = (short)f2bf(acc[i][j][2] + bv);
                pv.w = (short)f2bf(acc[i][j][3] + bv);
                // blocked: [h][m>>4][d][m&15]; m&15 = l4*4 (short4-aligned)
                *(short4*)(vblk +
                           ((size_t)(h * 256 + (m >> 4)) * 64 + d) * 16 +
                           (m & 15)) = pv;
            }
        } else if (s == 0) {
#pragma unroll
            for (int i = 0; i < 4; ++i) {
                const int m = row0 + wr * 64 + 16 * i + l4 * 4;
#pragma unroll
                for (int r = 0; r < 4; ++r)
                    qbh[((size_t)h * NTOK + m + r) * 64 + d] =
                        (short)f2bf(acc[i][j][r] + bv);
            }
        } else {   // s == 1: K -> blocked fragment layout
#pragma unroll
            for (int i = 0; i < 4; ++i) {
                const int m = row0 + wr * 64 + 16 * i + l4 * 4;
                // m>>5 uniform across r (m&31 <= 28, r <= 3)
                short* dst = kblk +
                    ((((size_t)(h * 128 + (m >> 5)) * 8 + (d >> 3)) * 32 +
                      (m & 31)) * 8 + (d & 7));
#pragma unroll
                for (int r = 0; r < 4; ++r)
                    dst[r * 8] = (short)f2bf(acc[i][j][r] + bv);
            }
        }
    }
}

// ---------------------------------------------------------------------------
// Flash attention v13: vB loads + relHs read HOISTED to the top of each
// iteration (before the S MFMAs) -- PV's V-wait is now covered by S-issue +
// softmax (~550cy) instead of softmax alone. Register-neutral vs v12 (the
// spill lesson). s_setprio(1) around both MFMA clusters (waves drift
// barrier-free -> role diversity for the CU scheduler). Prefetch clamps
// removed: one-past-the-end loads land in adjacent workspace, never consumed.
// WRITE_SIZE is the spill sentinel (~19 MB now; aob amplification floor 13).
// ---------------------------------------------------------------------------
union FlashSMem {
    float relHs[64][65];   // 16640 B  [kh][q-local] (LOG2E-scaled), loop
    float U[128 * 65];     // 33280 B  prologue overlay
    struct {
        float OEp[64][64]; // 16384 B  epilogue O-combine (aliases relHs;
        float lEp[64];     //   256 B  safe: barrier after last rh read)
    };
};

__global__ __launch_bounds__(256, 3) void flash_mfma_kernel(
    const short* __restrict__ qbh, const short* __restrict__ kblk,
    const short* __restrict__ vblk, const float* __restrict__ rpw,
    const float* __restrict__ rph, short* __restrict__ aob)
{
    __shared__ __align__(16) FlashSMem sm;

    const int t = threadIdx.x;
    const int qt = blockIdx.x, head = blockIdx.y;
    const int row0 = qt * 64;
    const int lane = t & 63, w = t >> 6;
    const int qh2 = w & 1, th = w >> 1;
    const int l31 = lane & 31, hf = lane >> 5;
    const size_t hB = (size_t)head * NTOK * 64;
    const float SC = 0.125f * LOG2E;

    // Q as 32x32 B-fragments: B[k=d][n=q], lane n=l31, k = 8*hf + j
    const int q = row0 + qh2 * 32 + l31;
    bf8v bQ[4];
    {
        const short* qsrc = qbh + hB + (size_t)q * 64;
#pragma unroll
        for (int ks = 0; ks < 4; ++ks)
            bQ[ks] = *(const bf8v*)(qsrc + ks * 16 + hf * 8);
    }

    // blocked-K fragment base; prefetch it=0 now (L2 latency hides under
    // the relW/relH prologue).  addr(h,it,th,t32,ks) =
    //   h*262144 + (it*4+th*2+t32)*2048 + (ks*2+hf)*256 + l31*8   [shorts]
    const short* kb = kblk + (size_t)head * 262144 + th * 4096 + hf * 256 +
                      (size_t)l31 * 8;
    bf8v kf[2][4];
#pragma unroll
    for (int t32 = 0; t32 < 2; ++t32)
#pragma unroll
        for (int ks = 0; ks < 4; ++ks)
            kf[t32][ks] = *(const bf8v*)(kb + t32 * 2048 + ks * 512);

    // blocked-V fragment base
    const short* vb2 = vblk + ((size_t)head * 256 * 64 + l31) * 16 + hf * 8;

    // --- fused relW: U[j][qw] = sum_d rpw[j][d] Q[qw][d]; row j=127 never
    // gathered (qw+63-kw <= 126) -> clamp its load to row 0.
#pragma unroll
    for (int jt2 = 0; jt2 < 2; ++jt2) {
        const int jt = 2 * th + jt2;
        int j = jt * 32 + l31;
        if (j > 126) j = 0;
        const float* asrc = rpw + (size_t)j * 64;
        f16v c = {};
#pragma unroll
        for (int ks = 0; ks < 4; ++ks) {
            float4 u0 = *(const float4*)(asrc + ks * 16 + hf * 8);
            float4 u1 = *(const float4*)(asrc + ks * 16 + hf * 8 + 4);
            c = __builtin_amdgcn_mfma_f32_32x32x16_bf16(
                pack8(u0, u1), bQ[ks], c, 0, 0, 0);
        }
#pragma unroll
        for (int reg = 0; reg < 16; ++reg)
            sm.U[(jt * 32 + (reg & 3) + 8 * (reg >> 2) + 4 * hf) * 65 +
                 qh2 * 32 + l31] = c[reg];
    }
    __syncthreads();
    // gather relW into packed-bf16 registers (LOG2E-scaled) -- 16 VGPRs
    const int qw = qh2 * 32 + l31;
    uint2 rwp[2][4];
#pragma unroll
    for (int t32 = 0; t32 < 2; ++t32)
#pragma unroll
        for (int g = 0; g < 4; ++g) {
            const int kw = t32 * 32 + 8 * g + 4 * hf;
            const float v0 = sm.U[(qw + 63 - kw) * 65 + qw] * LOG2E;
            const float v1 = sm.U[(qw + 62 - kw) * 65 + qw] * LOG2E;
            const float v2 = sm.U[(qw + 61 - kw) * 65 + qw] * LOG2E;
            const float v3 = sm.U[(qw + 60 - kw) * 65 + qw] * LOG2E;
            rwp[t32][g].x = pkbf(v1, v0);
            rwp[t32][g].y = pkbf(v3, v2);
        }
    __syncthreads();   // U reads done before relHs overwrites

    // --- fused relH: relHs[kh][q] = LOG2E * (rph[qt+63-kh] . Q[q])
    {
        const int kh = th * 32 + l31;
        const float* asrc = rph + (size_t)(qt + 63 - kh) * 64;
        f16v c = {};
#pragma unroll
        for (int ks = 0; ks < 4; ++ks) {
            float4 u0 = *(const float4*)(asrc + ks * 16 + hf * 8);
            float4 u1 = *(const float4*)(asrc + ks * 16 + hf * 8 + 4);
            u0.x *= LOG2E; u0.y *= LOG2E; u0.z *= LOG2E; u0.w *= LOG2E;
            u1.x *= LOG2E; u1.y *= LOG2E; u1.z *= LOG2E; u1.w *= LOG2E;
            c = __builtin_amdgcn_mfma_f32_32x32x16_bf16(
                pack8(u0, u1), bQ[ks], c, 0, 0, 0);
        }
#pragma unroll
        for (int reg = 0; reg < 16; ++reg)
            sm.relHs[th * 32 + (reg & 3) + 8 * (reg >> 2) + 4 * hf]
                    [qh2 * 32 + l31] = c[reg];
    }
    __syncthreads();   // relHs visible to all waves; LAST barrier before loop

    f16v O[2] = {{}, {}};   // ntile: d = ntile*32+l31; rows q (C layout)
    float lsum = 0.f;

#pragma unroll 1
    for (int it = 0; it < 32; ++it) {
        // V frags for THIS iter issued FIRST: PV's wait is covered by the
        // S-MFMA cluster + softmax, not softmax alone (v12 lesson: the
        // compiler preserves VMEM issue order; textual position matters).
        bf8v vB[2][2][2];   // [t32][ks2][nt]
        {
            const short* vit = vb2 + (size_t)(it * 8 + th * 4) * 1024;
#pragma unroll
            for (int t32 = 0; t32 < 2; ++t32)
#pragma unroll
                for (int ks2 = 0; ks2 < 2; ++ks2)
#pragma unroll
                    for (int nt = 0; nt < 2; ++nt)
                        vB[t32][ks2][nt] = *(const bf8v*)(
                            vit + ((size_t)(t32 * 2 + ks2) * 64 + nt * 32) *
                                      16);
        }
        const float rh = sm.relHs[2 * it + th][qw];

        // S^T: A = prefetched K frags (this wave's token half), B = bQ
        __builtin_amdgcn_s_setprio(1);
        f16v acc[2] = {{}, {}};
#pragma unroll
        for (int ks = 0; ks < 4; ++ks)
#pragma unroll
            for (int t32 = 0; t32 < 2; ++t32)
                acc[t32] = __builtin_amdgcn_mfma_f32_32x32x16_bf16(
                    kf[t32][ks], bQ[ks], acc[t32], 0, 0, 0);
        __builtin_amdgcn_s_setprio(0);

        // reload kf for it+1 into the SAME regs (WAR after last S MFMA);
        // no clamp: it=31 reads one tile past this head's K -- adjacent
        // workspace, value never consumed.
        {
            const short* kp = kb + (size_t)(it + 1) * 8192;
#pragma unroll
            for (int t32 = 0; t32 < 2; ++t32)
#pragma unroll
                for (int ks = 0; ks < 4; ++ks)
                    kf[t32][ks] =
                        *(const bf8v*)(kp + t32 * 2048 + ks * 512);
        }

        // e = exp2(SC*acc + rw + rh); pack pairs via v_cvt_pk_bf16_f32
        unsigned xg[2][4], yg[2][4];
#pragma unroll
        for (int t32 = 0; t32 < 2; ++t32) {
            float sub = 0.f;
#pragma unroll
            for (int g = 0; g < 4; ++g) {
                const unsigned u0 = rwp[t32][g].x;
                const unsigned u1 = rwp[t32][g].y;
                const float b0 = __uint_as_float(u0 << 16) + rh;
                const float b1 = __uint_as_float(u0 & 0xffff0000u) + rh;
                const float b2 = __uint_as_float(u1 << 16) + rh;
                const float b3 = __uint_as_float(u1 & 0xffff0000u) + rh;
                const float e0 = __builtin_amdgcn_exp2f(
                    fmaf(acc[t32][4 * g + 0], SC, b0));
                const float e1 = __builtin_amdgcn_exp2f(
                    fmaf(acc[t32][4 * g + 1], SC, b1));
                const float e2 = __builtin_amdgcn_exp2f(
                    fmaf(acc[t32][4 * g + 2], SC, b2));
                const float e3 = __builtin_amdgcn_exp2f(
                    fmaf(acc[t32][4 * g + 3], SC, b3));
                sub += (e0 + e1) + (e2 + e3);
                xg[t32][g] = cvtpk(e0, e1);   // lo=e0, hi=e1
                yg[t32][g] = cvtpk(e2, e3);   // lo=e2, hi=e3
            }
            lsum += sub;
        }

        // PV: A-frag via permlane32_swap pairs; B = direct-loaded V frags
        __builtin_amdgcn_s_setprio(1);
#pragma unroll
        for (int t32 = 0; t32 < 2; ++t32)
#pragma unroll
            for (int ks2 = 0; ks2 < 2; ++ks2) {
                auto px = __builtin_amdgcn_permlane32_swap(
                    xg[t32][2 * ks2], xg[t32][2 * ks2 + 1], false, false);
                auto py = __builtin_amdgcn_permlane32_swap(
                    yg[t32][2 * ks2], yg[t32][2 * ks2 + 1], false, false);
                int4 av;
                av.x = (int)px[0];
                av.y = (int)py[0];
                av.z = (int)px[1];
                av.w = (int)py[1];
                union { int4 i; bf8v v; } u; u.i = av;
#pragma unroll
                for (int nt = 0; nt < 2; ++nt)
                    O[nt] = __builtin_amdgcn_mfma_f32_32x32x16_bf16(
                        u.v, vB[t32][ks2][nt], O[nt], 0, 0, 0);
            }
        __builtin_amdgcn_s_setprio(0);
    }

    // epilogue: lanes l / l+32 share q -> reduce; then combine the two
    // token-half waves (th) via LDS union members, normalize, store.
    lsum += __shfl_xor(lsum, 32);
    __syncthreads();   // all waves past their last relHs read -> OEp may alias
    if (th == 1) {
#pragma unroll
        for (int nt = 0; nt < 2; ++nt)
#pragma unroll
            for (int reg = 0; reg < 16; ++reg) {
                const int qr = (reg & 3) + 8 * (reg >> 2) + 4 * hf;
                sm.OEp[qh2 * 32 + qr][nt * 32 + l31] = O[nt][reg];
            }
        if (lane < 32) sm.lEp[qh2 * 32 + l31] = lsum;
    }
    __syncthreads();
    if (th == 0) {
        lsum += sm.lEp[qh2 * 32 + l31];
        const float linv = 1.0f / lsum;
#pragma unroll
        for (int nt = 0; nt < 2; ++nt)
#pragma unroll
            for (int reg = 0; reg < 16; ++reg) {
                const int qr = (reg & 3) + 8 * (reg >> 2) + 4 * hf;
                const float li = __shfl(linv, qr);
                const float o =
                    O[nt][reg] + sm.OEp[qh2 * 32 + qr][nt * 32 + l31];
                aob[(size_t)(row0 + qh2 * 32 + qr) * 768 + head * 64 +
                    nt * 32 + l31] = (short)f2bf(o * li);
            }
    }
}

// ---------------------------------------------------------------------------
// proj GEMM (MFMA bf16), 64x64 tile -> grid (12,64)=768 blocks (3 blocks/CU).
// ---------------------------------------------------------------------------
__global__ __launch_bounds__(256) void proj_mfma_kernel(
    const short* __restrict__ aoh, const short* __restrict__ pwT,
    const float* __restrict__ bias, float* __restrict__ out)
{
    __shared__ __align__(16) short As[64 * 32];
    __shared__ __align__(16) short Bs[64 * 32];
    const int t = threadIdx.x;
    const int w = t >> 6, lane = t & 63;
    const int l15 = lane & 15, l4 = lane >> 4;
    const int wr = w >> 1, wc = w & 1;
    const int row0 = blockIdx.y * 64, col0 = blockIdx.x * 64;
    const int ldr = lane >> 2;
    const int ldk = (lane & 3) * 8;

    f4v acc[2][2] = {};
    const short* aBase = aoh + (size_t)(row0 + w * 16 + ldr) * 768 + ldk;
    const short* bBase = pwT + (size_t)(col0 + w * 16 + ldr) * 768 + ldk;

    for (int kk = 0; kk < 768; kk += 32) {
        __syncthreads();
        gload_lds16(aBase + kk, &As[(w * 16) * 32]);
        gload_lds16(bBase + kk, &Bs[(w * 16) * 32]);
        __syncthreads();
        bf8v af[2], bg[2];
#pragma unroll
        for (int i = 0; i < 2; ++i)
            af[i] = *(const bf8v*)&As[(wr * 32 + 16 * i + l15) * 32 + l4 * 8];
#pragma unroll
        for (int j = 0; j < 2; ++j)
            bg[j] = *(const bf8v*)&Bs[(wc * 32 + 16 * j + l15) * 32 + l4 * 8];
#pragma unroll
        for (int i = 0; i < 2; ++i)
#pragma unroll
            for (int j = 0; j < 2; ++j)
                acc[i][j] = __builtin_amdgcn_mfma_f32_16x16x32_bf16(
                    af[i], bg[j], acc[i][j], 0, 0, 0);
    }

#pragma unroll
    for (int j = 0; j < 2; ++j) {
        const int n = col0 + wc * 32 + 16 * j + l15;
        const float bv = bias[n];
#pragma unroll
        for (int i = 0; i < 2; ++i) {
            const int m = row0 + wr * 32 + 16 * i + l4 * 4;
#pragma unroll
            for (int r = 0; r < 4; ++r)
                out[(size_t)(m + r) * 768 + n] = acc[i][j][r] + bv;
        }
    }
}

// ---------------------------------------------------------------------------
extern "C" void kernel_launch(void* const* d_in, const int* in_sizes, int n_in,
                              void* d_out, int out_size, void* d_ws,
                              size_t ws_size, hipStream_t stream)
{
    (void)in_sizes; (void)n_in; (void)out_size; (void)ws_size;
    const float* x    = (const float*)d_in[0];
    const float* qkvw = (const float*)d_in[1];
    const float* qkvb = (const float*)d_in[2];
    const float* pw   = (const float*)d_in[3];
    const float* pb   = (const float*)d_in[4];
    const float* rph  = (const float*)d_in[5];
    const float* rpw  = (const float*)d_in[6];
    float* out = (float*)d_out;

    const size_t S = (size_t)NHEADS * NTOK * 64;  // 3,145,728 (= 4096*768)
    short* qbh  = (short*)d_ws;          // S bf16   q  [h][tok][d]
    short* kblk = qbh + S;               // S bf16   k  [h][tok/32][d/8][tok%32][d%8]
    short* vblk = kblk + S;              // S bf16   v  [h][tok/16][d][tok%16]
    short* xh   = vblk + S;              // S bf16   x [tok][c]; dead after
    short* aob  = xh;                    //   qkv -> aliased as attn out
    short* wqkvT = xh + S;               // 2304*768 bf16
    short* pwT  = wqkvT + (size_t)2304 * 768;  // 768*768 bf16
    // total ~29.6 MB

    prep_kernel<<<dim3(2112), 256, 0, stream>>>(x, qkvw, pw, xh, wqkvT, pwT);
    qkv_mfma_kernel<<<dim3(24, 32), 256, 0, stream>>>(xh, wqkvT, qkvb,
                                                      qbh, kblk, vblk);
    flash_mfma_kernel<<<dim3(64, NHEADS), 256, 0, stream>>>(qbh, kblk, vblk,
                                                            rpw, rph, aob);
    proj_mfma_kernel<<<dim3(12, 64), 256, 0, stream>>>(aob, pwT, pb, out);
}

// Round 5
// 233.630 us; speedup vs baseline: 1.1156x; 1.1156x over previous
//
#include <hip/hip_runtime.h>
#include <math.h>

// Problem constants: B=1, H=W=64 (N=4096), C=768, 12 heads x hd=64.
#define NHEADS 12
#define NTOK 4096
#define LOG2E 1.44269504f

typedef __attribute__((ext_vector_type(8))) short bf8v;    // 8 x bf16
typedef __attribute__((ext_vector_type(4))) float f4v;     // 16x16 C/D frag
typedef __attribute__((ext_vector_type(16))) float f16v;   // 32x32 C/D frag

__device__ __forceinline__ unsigned short f2bf(float f) {
  unsigned int u = __float_as_uint(f);
  u += 0x7fffu + ((u >> 16) & 1u);   // RNE
  return (unsigned short)(u >> 16);
}
__device__ __forceinline__ bf8v pack8(float4 a, float4 b) {
  bf8v v;
  v[0] = (short)f2bf(a.x); v[1] = (short)f2bf(a.y);
  v[2] = (short)f2bf(a.z); v[3] = (short)f2bf(a.w);
  v[4] = (short)f2bf(b.x); v[5] = (short)f2bf(b.y);
  v[6] = (short)f2bf(b.z); v[7] = (short)f2bf(b.w);
  return v;
}
// pack two f32 (round via +0x8000) into (hi|lo) bf16 pair
__device__ __forceinline__ unsigned pkbf(float hi, float lo) {
  return __builtin_amdgcn_perm(__float_as_uint(hi) + 0x8000u,
                               __float_as_uint(lo) + 0x8000u, 0x07060302u);
}
// pack two f32 into (hi=b | lo=a) bf16 pair in ONE instruction
__device__ __forceinline__ unsigned cvtpk(float lo, float hi) {
  unsigned r;
  asm("v_cvt_pk_bf16_f32 %0, %1, %2" : "=v"(r) : "v"(lo), "v"(hi));
  return r;
}
__device__ __forceinline__ void gload_lds16(const void* g, void* l) {
  __builtin_amdgcn_global_load_lds(
      (const __attribute__((address_space(1))) void*)g,
      (__attribute__((address_space(3))) void*)l, 16, 0, 0);
}

// ---------------------------------------------------------------------------
// prep: unified x->bf16 cvt + qkv_w / proj_w transpose-cvt (one launch).
// blocks [0,1536): cvt; [1536,1968): tcvt qkvw; [1968,2112): tcvt pw.
// ---------------------------------------------------------------------------
__device__ __forceinline__ void tcvt_body(
    const float* __restrict__ in, short* __restrict__ out, int R, int C,
    int bx, int by, int t, float (*Ts)[65])
{
    const int bc = bx * 64, br = by * 64;
    {
        const int r = t >> 2, c0 = (t & 3) * 16;
        const float* src = in + (size_t)(br + r) * C + bc + c0;
#pragma unroll
        for (int i = 0; i < 4; ++i) {
            float4 a = *(const float4*)(src + 4 * i);
            Ts[r][c0 + 4 * i + 0] = a.x;
            Ts[r][c0 + 4 * i + 1] = a.y;
            Ts[r][c0 + 4 * i + 2] = a.z;
            Ts[r][c0 + 4 * i + 3] = a.w;
        }
    }
    __syncthreads();
    const int c = t >> 2, r0 = (t & 3) * 16;
    short* dst = out + (size_t)(bc + c) * R + br + r0;
#pragma unroll
    for (int p = 0; p < 2; ++p) {
        bf8v v;
#pragma unroll
        for (int i = 0; i < 8; ++i) v[i] = (short)f2bf(Ts[r0 + p * 8 + i][c]);
        *(bf8v*)(dst + p * 8) = v;
    }
}

__global__ __launch_bounds__(256) void prep_kernel(
    const float* __restrict__ x, const float* __restrict__ qkvw,
    const float* __restrict__ pw, short* __restrict__ xh,
    short* __restrict__ wqkvT, short* __restrict__ pwT)
{
    __shared__ float Ts[64][65];
    const int bid = blockIdx.x, t = threadIdx.x;
    if (bid < 1536) {
        const size_t i = ((size_t)bid * 256 + t) * 8;
        float4 a = *(const float4*)(x + i);
        float4 b = *(const float4*)(x + i + 4);
        *(bf8v*)(xh + i) = pack8(a, b);
    } else if (bid < 1968) {
        const int idx = bid - 1536;
        tcvt_body(qkvw, wqkvT, 768, 2304, idx % 36, idx / 36, t, Ts);
    } else {
        const int idx = bid - 1968;
        tcvt_body(pw, pwT, 768, 768, idx % 12, idx / 12, t, Ts);
    }
}

// ---------------------------------------------------------------------------
// QKV GEMM (MFMA bf16): 128x96 tile, grid (24,32)=768 blocks.
// V epilogue writes BLOCKED layout vblk[h][tok/16][d][tok%16].
// K epilogue writes blocked MFMA-A-fragment-order layout
//   kblk[h][tok>>5][d>>3][tok&31][d&7]
// ---------------------------------------------------------------------------
__global__ __launch_bounds__(256) void qkv_mfma_kernel(
    const short* __restrict__ xh, const short* __restrict__ wT,
    const float* __restrict__ bias, short* __restrict__ qbh,
    short* __restrict__ kblk, short* __restrict__ vblk)
{
    __shared__ __align__(16) short As[128 * 32];
    __shared__ __align__(16) short Bs[96 * 32];
    const int t = threadIdx.x;
    const int w = t >> 6, lane = t & 63;
    const int l15 = lane & 15, l4 = lane >> 4;
    const int wr = w >> 1, wc = w & 1;
    const int row0 = blockIdx.y * 128, col0 = blockIdx.x * 96;
    const int ldr = lane >> 2;
    const int ldk = (lane & 3) * 8;

    f4v acc[4][3] = {};
    const short* aBase = xh + (size_t)(row0 + w * 32 + ldr) * 768 + ldk;
    const short* bBase0 = wT + (size_t)(col0 + w * 16 + ldr) * 768 + ldk;
    const short* bBase1 = wT + (size_t)(col0 + 64 + w * 16 + ldr) * 768 + ldk;

    for (int kk = 0; kk < 768; kk += 32) {
        __syncthreads();
#pragma unroll
        for (int c = 0; c < 2; ++c)
            gload_lds16(aBase + (size_t)c * 16 * 768 + kk,
                        &As[(w * 32 + c * 16) * 32]);
        gload_lds16(bBase0 + kk, &Bs[(w * 16) * 32]);
        if (w < 2)   // wave-uniform: waves 0,1 stage B chunks 4,5
            gload_lds16(bBase1 + kk, &Bs[(64 + w * 16) * 32]);
        __syncthreads();
        bf8v af[4], bg[3];
#pragma unroll
        for (int i = 0; i < 4; ++i)
            af[i] = *(const bf8v*)&As[(wr * 64 + 16 * i + l15) * 32 + l4 * 8];
#pragma unroll
        for (int j = 0; j < 3; ++j)
            bg[j] = *(const bf8v*)&Bs[(wc * 48 + 16 * j + l15) * 32 + l4 * 8];
#pragma unroll
        for (int i = 0; i < 4; ++i)
#pragma unroll
            for (int j = 0; j < 3; ++j)
                acc[i][j] = __builtin_amdgcn_mfma_f32_16x16x32_bf16(
                    af[i], bg[j], acc[i][j], 0, 0, 0);
    }

#pragma unroll
    for (int j = 0; j < 3; ++j) {
        const int n = col0 + wc * 48 + 16 * j + l15;
        const int s = n / 768;            // block-uniform (96 | 768)
        const int rm = n - s * 768;
        const int h = rm >> 6, d = rm & 63;
        const float bv = bias[n];
        if (s == 2) {
#pragma unroll
            for (int i = 0; i < 4; ++i) {
                const int m = row0 + wr * 64 + 16 * i + l4 * 4;
                short4 pv;
                pv.x = (short)f2bf(acc[i][j][0] + bv);
                pv.y = (short)f2bf(acc[i][j][1] + bv);
                pv.z = (short)f2bf(acc[i][j][2] + bv);
                pv.w = (short)f2bf(acc[i][j][3] + bv);
                // blocked: [h][m>>4][d][m&15]; m&15 = l4*4 (short4-aligned)
                *(short4*)(vblk +
                           ((size_t)(h * 256 + (m >> 4)) * 64 + d) * 16 +
                           (m & 15)) = pv;
            }
        } else if (s == 0) {
#pragma unroll
            for (int i = 0; i < 4; ++i) {
                const int m = row0 + wr * 64 + 16 * i + l4 * 4;
#pragma unroll
                for (int r = 0; r < 4; ++r)
                    qbh[((size_t)h * NTOK + m + r) * 64 + d] =
                        (short)f2bf(acc[i][j][r] + bv);
            }
        } else {   // s == 1: K -> blocked fragment layout
#pragma unroll
            for (int i = 0; i < 4; ++i) {
                const int m = row0 + wr * 64 + 16 * i + l4 * 4;
                // m>>5 uniform across r (m&31 <= 28, r <= 3)
                short* dst = kblk +
                    ((((size_t)(h * 128 + (m >> 5)) * 8 + (d >> 3)) * 32 +
                      (m & 31)) * 8 + (d & 7));
#pragma unroll
                for (int r = 0; r < 4; ++r)
                    dst[r * 8] = (short)f2bf(acc[i][j][r] + bv);
            }
        }
    }
}

// ---------------------------------------------------------------------------
// Flash attention v15: v12 (verified, 87us) with KV range split across
// blockIdx.z -- z=0 runs iterations 0..15, z=1 runs 16..31. Every per-
// iteration address stream is BYTE-IDENTICAL to v12's; only the it range
// and the output differ. Each z-block writes unnormalized partial O (f32)
// + partial lsum to workspace; ocomb_kernel merges. Grid 768 -> 1536 =
// 4 blocks/CU = 16 waves/CU (was grid-capped at 3/12). WRITE_SIZE now
// includes 25 MB opart BY DESIGN -- VGPR_Count (84) is the spill sentinel.
// ---------------------------------------------------------------------------
union FlashSMem {
    float relHs[64][65];   // 16640 B  [kh][q-local] (LOG2E-scaled), loop
    float U[128 * 65];     // 33280 B  prologue overlay
    struct {
        float OEp[64][64]; // 16384 B  epilogue O-combine (aliases relHs;
        float lEp[64];     //   256 B  safe: barrier after last rh read)
    };
};

__global__ __launch_bounds__(256, 3) void flash_mfma_kernel(
    const short* __restrict__ qbh, const short* __restrict__ kblk,
    const short* __restrict__ vblk, const float* __restrict__ rpw,
    const float* __restrict__ rph, float* __restrict__ opart,
    float* __restrict__ lsums)
{
    __shared__ __align__(16) FlashSMem sm;

    const int t = threadIdx.x;
    const int qt = blockIdx.x, head = blockIdx.y, zz = blockIdx.z;
    const int row0 = qt * 64;
    const int lane = t & 63, w = t >> 6;
    const int qh2 = w & 1, th = w >> 1;
    const int l31 = lane & 31, hf = lane >> 5;
    const size_t hB = (size_t)head * NTOK * 64;
    const float SC = 0.125f * LOG2E;

    // Q as 32x32 B-fragments: B[k=d][n=q], lane n=l31, k = 8*hf + j
    const int q = row0 + qh2 * 32 + l31;
    bf8v bQ[4];
    {
        const short* qsrc = qbh + hB + (size_t)q * 64;
#pragma unroll
        for (int ks = 0; ks < 4; ++ks)
            bQ[ks] = *(const bf8v*)(qsrc + ks * 16 + hf * 8);
    }

    // blocked-K fragment base; prefetch this z's first tile now.
    //   addr(h,it,th,t32,ks) =
    //   h*262144 + (it*4+th*2+t32)*2048 + (ks*2+hf)*256 + l31*8   [shorts]
    const short* kb = kblk + (size_t)head * 262144 + th * 4096 + hf * 256 +
                      (size_t)l31 * 8;
    bf8v kf[2][4];
#pragma unroll
    for (int t32 = 0; t32 < 2; ++t32)
#pragma unroll
        for (int ks = 0; ks < 4; ++ks)
            kf[t32][ks] = *(const bf8v*)(kb + (size_t)zz * 131072 +
                                         t32 * 2048 + ks * 512);

    // blocked-V fragment base
    const short* vb2 = vblk + ((size_t)head * 256 * 64 + l31) * 16 + hf * 8;

    // --- fused relW: U[j][qw] = sum_d rpw[j][d] Q[qw][d]; row j=127 never
    // gathered (qw+63-kw <= 126) -> clamp its load to row 0.
#pragma unroll
    for (int jt2 = 0; jt2 < 2; ++jt2) {
        const int jt = 2 * th + jt2;
        int j = jt * 32 + l31;
        if (j > 126) j = 0;
        const float* asrc = rpw + (size_t)j * 64;
        f16v c = {};
#pragma unroll
        for (int ks = 0; ks < 4; ++ks) {
            float4 u0 = *(const float4*)(asrc + ks * 16 + hf * 8);
            float4 u1 = *(const float4*)(asrc + ks * 16 + hf * 8 + 4);
            c = __builtin_amdgcn_mfma_f32_32x32x16_bf16(
                pack8(u0, u1), bQ[ks], c, 0, 0, 0);
        }
#pragma unroll
        for (int reg = 0; reg < 16; ++reg)
            sm.U[(jt * 32 + (reg & 3) + 8 * (reg >> 2) + 4 * hf) * 65 +
                 qh2 * 32 + l31] = c[reg];
    }
    __syncthreads();
    // gather relW into packed-bf16 registers (LOG2E-scaled) -- 16 VGPRs
    const int qw = qh2 * 32 + l31;
    uint2 rwp[2][4];
#pragma unroll
    for (int t32 = 0; t32 < 2; ++t32)
#pragma unroll
        for (int g = 0; g < 4; ++g) {
            const int kw = t32 * 32 + 8 * g + 4 * hf;
            const float v0 = sm.U[(qw + 63 - kw) * 65 + qw] * LOG2E;
            const float v1 = sm.U[(qw + 62 - kw) * 65 + qw] * LOG2E;
            const float v2 = sm.U[(qw + 61 - kw) * 65 + qw] * LOG2E;
            const float v3 = sm.U[(qw + 60 - kw) * 65 + qw] * LOG2E;
            rwp[t32][g].x = pkbf(v1, v0);
            rwp[t32][g].y = pkbf(v3, v2);
        }
    __syncthreads();   // U reads done before relHs overwrites

    // --- fused relH: relHs[kh][q] = LOG2E * (rph[qt+63-kh] . Q[q])
    {
        const int kh = th * 32 + l31;
        const float* asrc = rph + (size_t)(qt + 63 - kh) * 64;
        f16v c = {};
#pragma unroll
        for (int ks = 0; ks < 4; ++ks) {
            float4 u0 = *(const float4*)(asrc + ks * 16 + hf * 8);
            float4 u1 = *(const float4*)(asrc + ks * 16 + hf * 8 + 4);
            u0.x *= LOG2E; u0.y *= LOG2E; u0.z *= LOG2E; u0.w *= LOG2E;
            u1.x *= LOG2E; u1.y *= LOG2E; u1.z *= LOG2E; u1.w *= LOG2E;
            c = __builtin_amdgcn_mfma_f32_32x32x16_bf16(
                pack8(u0, u1), bQ[ks], c, 0, 0, 0);
        }
#pragma unroll
        for (int reg = 0; reg < 16; ++reg)
            sm.relHs[th * 32 + (reg & 3) + 8 * (reg >> 2) + 4 * hf]
                    [qh2 * 32 + l31] = c[reg];
    }
    __syncthreads();   // relHs visible to all waves; LAST barrier before loop

    f16v O[2] = {{}, {}};   // ntile: d = ntile*32+l31; rows q (C layout)
    float lsum = 0.f;

    for (int it = zz * 16; it < zz * 16 + 16; ++it) {
        // S^T: A = prefetched K frags (this wave's token half), B = bQ
        f16v acc[2] = {{}, {}};
#pragma unroll
        for (int ks = 0; ks < 4; ++ks)
#pragma unroll
            for (int t32 = 0; t32 < 2; ++t32)
                acc[t32] = __builtin_amdgcn_mfma_f32_32x32x16_bf16(
                    kf[t32][ks], bQ[ks], acc[t32], 0, 0, 0);

        // V frags FIRST (consumed this iter at PV -> PV waits vmcnt(8),
        // leaving the kf reload below in flight)
        bf8v vB[2][2][2];   // [t32][ks2][nt]
        {
            const short* vit = vb2 + (size_t)(it * 8 + th * 4) * 1024;
#pragma unroll
            for (int t32 = 0; t32 < 2; ++t32)
#pragma unroll
                for (int ks2 = 0; ks2 < 2; ++ks2)
#pragma unroll
                    for (int nt = 0; nt < 2; ++nt)
                        vB[t32][ks2][nt] = *(const bf8v*)(
                            vit + ((size_t)(t32 * 2 + ks2) * 64 + nt * 32) *
                                      16);
        }

        // reload kf for it+1 into the SAME regs (WAR after last S MFMA);
        // z=1 last iter reads one tile past this head's K -- adjacent
        // workspace, valid memory, value never consumed.
        {
            const short* kp = kb + (size_t)(it + 1) * 8192;
#pragma unroll
            for (int t32 = 0; t32 < 2; ++t32)
#pragma unroll
                for (int ks = 0; ks < 4; ++ks)
                    kf[t32][ks] =
                        *(const bf8v*)(kp + t32 * 2048 + ks * 512);
        }

        const float rh = sm.relHs[2 * it + th][qw];

        // e = exp2(SC*acc + rw + rh); pack pairs via v_cvt_pk_bf16_f32
        unsigned xg[2][4], yg[2][4];
#pragma unroll
        for (int t32 = 0; t32 < 2; ++t32) {
            float sub = 0.f;
#pragma unroll
            for (int g = 0; g < 4; ++g) {
                const unsigned u0 = rwp[t32][g].x;
                const unsigned u1 = rwp[t32][g].y;
                const float b0 = __uint_as_float(u0 << 16) + rh;
                const float b1 = __uint_as_float(u0 & 0xffff0000u) + rh;
                const float b2 = __uint_as_float(u1 << 16) + rh;
                const float b3 = __uint_as_float(u1 & 0xffff0000u) + rh;
                const float e0 = __builtin_amdgcn_exp2f(
                    fmaf(acc[t32][4 * g + 0], SC, b0));
                const float e1 = __builtin_amdgcn_exp2f(
                    fmaf(acc[t32][4 * g + 1], SC, b1));
                const float e2 = __builtin_amdgcn_exp2f(
                    fmaf(acc[t32][4 * g + 2], SC, b2));
                const float e3 = __builtin_amdgcn_exp2f(
                    fmaf(acc[t32][4 * g + 3], SC, b3));
                sub += (e0 + e1) + (e2 + e3);
                xg[t32][g] = cvtpk(e0, e1);   // lo=e0, hi=e1
                yg[t32][g] = cvtpk(e2, e3);   // lo=e2, hi=e3
            }
            lsum += sub;
        }

        // PV: A-frag via permlane32_swap pairs; B = direct-loaded V frags
#pragma unroll
        for (int t32 = 0; t32 < 2; ++t32)
#pragma unroll
            for (int ks2 = 0; ks2 < 2; ++ks2) {
                auto px = __builtin_amdgcn_permlane32_swap(
                    xg[t32][2 * ks2], xg[t32][2 * ks2 + 1], false, false);
                auto py = __builtin_amdgcn_permlane32_swap(
                    yg[t32][2 * ks2], yg[t32][2 * ks2 + 1], false, false);
                int4 av;
                av.x = (int)px[0];
                av.y = (int)py[0];
                av.z = (int)px[1];
                av.w = (int)py[1];
                union { int4 i; bf8v v; } u; u.i = av;
#pragma unroll
                for (int nt = 0; nt < 2; ++nt)
                    O[nt] = __builtin_amdgcn_mfma_f32_32x32x16_bf16(
                        u.v, vB[t32][ks2][nt], O[nt], 0, 0, 0);
            }
    }

    // epilogue: lanes l / l+32 share q -> reduce; combine the two token-half
    // waves (th) via LDS; store UNNORMALIZED partial O (f32) + partial lsum.
    lsum += __shfl_xor(lsum, 32);
    __syncthreads();   // all waves past their last relHs read -> OEp may alias
    if (th == 1) {
#pragma unroll
        for (int nt = 0; nt < 2; ++nt)
#pragma unroll
            for (int reg = 0; reg < 16; ++reg) {
                const int qr = (reg & 3) + 8 * (reg >> 2) + 4 * hf;
                sm.OEp[qh2 * 32 + qr][nt * 32 + l31] = O[nt][reg];
            }
        if (lane < 32) sm.lEp[qh2 * 32 + l31] = lsum;
    }
    __syncthreads();
    if (th == 0) {
        lsum += sm.lEp[qh2 * 32 + l31];
#pragma unroll
        for (int nt = 0; nt < 2; ++nt)
#pragma unroll
            for (int reg = 0; reg < 16; ++reg) {
                const int qr = (reg & 3) + 8 * (reg >> 2) + 4 * hf;
                opart[((size_t)(zz * NTOK) + row0 + qh2 * 32 + qr) * 768 +
                      head * 64 + nt * 32 + l31] =
                    O[nt][reg] + sm.OEp[qh2 * 32 + qr][nt * 32 + l31];
            }
        if (lane < 32)
            lsums[(size_t)zz * (NHEADS * NTOK) + head * NTOK + row0 +
                  qh2 * 32 + l31] = lsum;
    }
}

// ---------------------------------------------------------------------------
// O-combine: aob[tok][col] = (O0+O1)[tok][col] / (l0+l1)[head][tok], bf16.
// grid 1024 blocks x 256 thr; wave handles one token, lane 3 float4 chunks.
// ~32 MB traffic -> ~6-8 us.
// ---------------------------------------------------------------------------
__global__ __launch_bounds__(256) void ocomb_kernel(
    const float* __restrict__ opart, const float* __restrict__ lsums,
    short* __restrict__ aob)
{
    const int t = threadIdx.x;
    const int wv = t >> 6, lane = t & 63;
    const int tok = blockIdx.x * 4 + wv;
    const float* o0 = opart + (size_t)tok * 768;
    const float* o1 = opart + (size_t)(NTOK + tok) * 768;
#pragma unroll
    for (int c = 0; c < 3; ++c) {
        const int col = (lane + c * 64) * 4;   // cols col..col+3 (one head)
        const int h = col >> 6;
        const float l = lsums[(size_t)h * NTOK + tok] +
                        lsums[(size_t)(NHEADS + h) * NTOK + tok];
        const float li = 1.0f / l;
        float4 a = *(const float4*)(o0 + col);
        float4 b = *(const float4*)(o1 + col);
        short4 r;
        r.x = (short)f2bf((a.x + b.x) * li);
        r.y = (short)f2bf((a.y + b.y) * li);
        r.z = (short)f2bf((a.z + b.z) * li);
        r.w = (short)f2bf((a.w + b.w) * li);
        *(short4*)(aob + (size_t)tok * 768 + col) = r;
    }
}

// ---------------------------------------------------------------------------
// proj GEMM (MFMA bf16), 64x64 tile -> grid (12,64)=768 blocks (3 blocks/CU).
// ---------------------------------------------------------------------------
__global__ __launch_bounds__(256) void proj_mfma_kernel(
    const short* __restrict__ aoh, const short* __restrict__ pwT,
    const float* __restrict__ bias, float* __restrict__ out)
{
    __shared__ __align__(16) short As[64 * 32];
    __shared__ __align__(16) short Bs[64 * 32];
    const int t = threadIdx.x;
    const int w = t >> 6, lane = t & 63;
    const int l15 = lane & 15, l4 = lane >> 4;
    const int wr = w >> 1, wc = w & 1;
    const int row0 = blockIdx.y * 64, col0 = blockIdx.x * 64;
    const int ldr = lane >> 2;
    const int ldk = (lane & 3) * 8;

    f4v acc[2][2] = {};
    const short* aBase = aoh + (size_t)(row0 + w * 16 + ldr) * 768 + ldk;
    const short* bBase = pwT + (size_t)(col0 + w * 16 + ldr) * 768 + ldk;

    for (int kk = 0; kk < 768; kk += 32) {
        __syncthreads();
        gload_lds16(aBase + kk, &As[(w * 16) * 32]);
        gload_lds16(bBase + kk, &Bs[(w * 16) * 32]);
        __syncthreads();
        bf8v af[2], bg[2];
#pragma unroll
        for (int i = 0; i < 2; ++i)
            af[i] = *(const bf8v*)&As[(wr * 32 + 16 * i + l15) * 32 + l4 * 8];
#pragma unroll
        for (int j = 0; j < 2; ++j)
            bg[j] = *(const bf8v*)&Bs[(wc * 32 + 16 * j + l15) * 32 + l4 * 8];
#pragma unroll
        for (int i = 0; i < 2; ++i)
#pragma unroll
            for (int j = 0; j < 2; ++j)
                acc[i][j] = __builtin_amdgcn_mfma_f32_16x16x32_bf16(
                    af[i], bg[j], acc[i][j], 0, 0, 0);
    }

#pragma unroll
    for (int j = 0; j < 2; ++j) {
        const int n = col0 + wc * 32 + 16 * j + l15;
        const float bv = bias[n];
#pragma unroll
        for (int i = 0; i < 2; ++i) {
            const int m = row0 + wr * 32 + 16 * i + l4 * 4;
#pragma unroll
            for (int r = 0; r < 4; ++r)
                out[(size_t)(m + r) * 768 + n] = acc[i][j][r] + bv;
        }
    }
}

// ---------------------------------------------------------------------------
extern "C" void kernel_launch(void* const* d_in, const int* in_sizes, int n_in,
                              void* d_out, int out_size, void* d_ws,
                              size_t ws_size, hipStream_t stream)
{
    (void)in_sizes; (void)n_in; (void)out_size; (void)ws_size;
    const float* x    = (const float*)d_in[0];
    const float* qkvw = (const float*)d_in[1];
    const float* qkvb = (const float*)d_in[2];
    const float* pw   = (const float*)d_in[3];
    const float* pb   = (const float*)d_in[4];
    const float* rph  = (const float*)d_in[5];
    const float* rpw  = (const float*)d_in[6];
    float* out = (float*)d_out;

    const size_t S = (size_t)NHEADS * NTOK * 64;  // 3,145,728 (= 4096*768)
    short* qbh  = (short*)d_ws;          // S bf16   q  [h][tok][d]
    short* kblk = qbh + S;               // S bf16   k  [h][tok/32][d/8][tok%32][d%8]
    short* vblk = kblk + S;              // S bf16   v  [h][tok/16][d][tok%16]
    short* xh   = vblk + S;              // S bf16   x [tok][c]; dead after
    short* aob  = xh;                    //   qkv -> aliased as attn out
    short* wqkvT = xh + S;               // 2304*768 bf16
    short* pwT  = wqkvT + (size_t)2304 * 768;  // 768*768 bf16
    float* opart = (float*)(pwT + (size_t)768 * 768);  // 2*4096*768 f32 (25.2MB)
    float* lsums = opart + (size_t)2 * NTOK * 768;     // 2*12*4096 f32
    // total ~55.5 MB

    prep_kernel<<<dim3(2112), 256, 0, stream>>>(x, qkvw, pw, xh, wqkvT, pwT);
    qkv_mfma_kernel<<<dim3(24, 32), 256, 0, stream>>>(xh, wqkvT, qkvb,
                                                      qbh, kblk, vblk);
    flash_mfma_kernel<<<dim3(64, NHEADS, 2), 256, 0, stream>>>(
        qbh, kblk, vblk, rpw, rph, opart, lsums);
    ocomb_kernel<<<dim3(NTOK / 4), 256, 0, stream>>>(opart, lsums, aob);
    proj_mfma_kernel<<<dim3(12, 64), 256, 0, stream>>>(aob, pwT, pb, out);
}

// Round 7
// 210.551 us; speedup vs baseline: 1.2379x; 1.1096x over previous
//
#include <hip/hip_runtime.h>
#include <math.h>

// Problem constants: B=1, H=W=64 (N=4096), C=768, 12 heads x hd=64.
#define NHEADS 12
#define NTOK 4096
#define LOG2E 1.44269504f

typedef __attribute__((ext_vector_type(8))) short bf8v;    // 8 x bf16
typedef __attribute__((ext_vector_type(4))) float f4v;     // 16x16 C/D frag
typedef __attribute__((ext_vector_type(16))) float f16v;   // 32x32 C/D frag

__device__ __forceinline__ unsigned short f2bf(float f) {
  unsigned int u = __float_as_uint(f);
  u += 0x7fffu + ((u >> 16) & 1u);   // RNE
  return (unsigned short)(u >> 16);
}
__device__ __forceinline__ bf8v pack8(float4 a, float4 b) {
  bf8v v;
  v[0] = (short)f2bf(a.x); v[1] = (short)f2bf(a.y);
  v[2] = (short)f2bf(a.z); v[3] = (short)f2bf(a.w);
  v[4] = (short)f2bf(b.x); v[5] = (short)f2bf(b.y);
  v[6] = (short)f2bf(b.z); v[7] = (short)f2bf(b.w);
  return v;
}
// pack two f32 (round via +0x8000) into (hi|lo) bf16 pair
__device__ __forceinline__ unsigned pkbf(float hi, float lo) {
  return __builtin_amdgcn_perm(__float_as_uint(hi) + 0x8000u,
                               __float_as_uint(lo) + 0x8000u, 0x07060302u);
}
// pack two f32 into (hi=b | lo=a) bf16 pair in ONE instruction
__device__ __forceinline__ unsigned cvtpk(float lo, float hi) {
  unsigned r;
  asm("v_cvt_pk_bf16_f32 %0, %1, %2" : "=v"(r) : "v"(lo), "v"(hi));
  return r;
}
__device__ __forceinline__ void gload_lds16(const void* g, void* l) {
  __builtin_amdgcn_global_load_lds(
      (const __attribute__((address_space(1))) void*)g,
      (__attribute__((address_space(3))) void*)l, 16, 0, 0);
}

// ---------------------------------------------------------------------------
// prep: unified x->bf16 cvt + qkv_w / proj_w transpose-cvt (one launch).
// blocks [0,1536): cvt; [1536,1968): tcvt qkvw; [1968,2112): tcvt pw.
// ---------------------------------------------------------------------------
__device__ __forceinline__ void tcvt_body(
    const float* __restrict__ in, short* __restrict__ out, int R, int C,
    int bx, int by, int t, float (*Ts)[65])
{
    const int bc = bx * 64, br = by * 64;
    {
        const int r = t >> 2, c0 = (t & 3) * 16;
        const float* src = in + (size_t)(br + r) * C + bc + c0;
#pragma unroll
        for (int i = 0; i < 4; ++i) {
            float4 a = *(const float4*)(src + 4 * i);
            Ts[r][c0 + 4 * i + 0] = a.x;
            Ts[r][c0 + 4 * i + 1] = a.y;
            Ts[r][c0 + 4 * i + 2] = a.z;
            Ts[r][c0 + 4 * i + 3] = a.w;
        }
    }
    __syncthreads();
    const int c = t >> 2, r0 = (t & 3) * 16;
    short* dst = out + (size_t)(bc + c) * R + br + r0;
#pragma unroll
    for (int p = 0; p < 2; ++p) {
        bf8v v;
#pragma unroll
        for (int i = 0; i < 8; ++i) v[i] = (short)f2bf(Ts[r0 + p * 8 + i][c]);
        *(bf8v*)(dst + p * 8) = v;
    }
}

__global__ __launch_bounds__(256) void prep_kernel(
    const float* __restrict__ x, const float* __restrict__ qkvw,
    const float* __restrict__ pw, short* __restrict__ xh,
    short* __restrict__ wqkvT, short* __restrict__ pwT)
{
    __shared__ float Ts[64][65];
    const int bid = blockIdx.x, t = threadIdx.x;
    if (bid < 1536) {
        const size_t i = ((size_t)bid * 256 + t) * 8;
        float4 a = *(const float4*)(x + i);
        float4 b = *(const float4*)(x + i + 4);
        *(bf8v*)(xh + i) = pack8(a, b);
    } else if (bid < 1968) {
        const int idx = bid - 1536;
        tcvt_body(qkvw, wqkvT, 768, 2304, idx % 36, idx / 36, t, Ts);
    } else {
        const int idx = bid - 1968;
        tcvt_body(pw, pwT, 768, 768, idx % 12, idx / 12, t, Ts);
    }
}

// ---------------------------------------------------------------------------
// QKV GEMM (MFMA bf16): 128x96 tile, grid (24,32)=768 blocks.
// V epilogue writes BLOCKED layout vblk[h][tok/16][d][tok%16].
// K epilogue writes blocked MFMA-A-fragment-order layout
//   kblk[h][tok>>5][d>>3][tok&31][d&7]
// ---------------------------------------------------------------------------
__global__ __launch_bounds__(256) void qkv_mfma_kernel(
    const short* __restrict__ xh, const short* __restrict__ wT,
    const float* __restrict__ bias, short* __restrict__ qbh,
    short* __restrict__ kblk, short* __restrict__ vblk)
{
    __shared__ __align__(16) short As[128 * 32];
    __shared__ __align__(16) short Bs[96 * 32];
    const int t = threadIdx.x;
    const int w = t >> 6, lane = t & 63;
    const int l15 = lane & 15, l4 = lane >> 4;
    const int wr = w >> 1, wc = w & 1;
    const int row0 = blockIdx.y * 128, col0 = blockIdx.x * 96;
    const int ldr = lane >> 2;
    const int ldk = (lane & 3) * 8;

    f4v acc[4][3] = {};
    const short* aBase = xh + (size_t)(row0 + w * 32 + ldr) * 768 + ldk;
    const short* bBase0 = wT + (size_t)(col0 + w * 16 + ldr) * 768 + ldk;
    const short* bBase1 = wT + (size_t)(col0 + 64 + w * 16 + ldr) * 768 + ldk;

    for (int kk = 0; kk < 768; kk += 32) {
        __syncthreads();
#pragma unroll
        for (int c = 0; c < 2; ++c)
            gload_lds16(aBase + (size_t)c * 16 * 768 + kk,
                        &As[(w * 32 + c * 16) * 32]);
        gload_lds16(bBase0 + kk, &Bs[(w * 16) * 32]);
        if (w < 2)   // wave-uniform: waves 0,1 stage B chunks 4,5
            gload_lds16(bBase1 + kk, &Bs[(64 + w * 16) * 32]);
        __syncthreads();
        bf8v af[4], bg[3];
#pragma unroll
        for (int i = 0; i < 4; ++i)
            af[i] = *(const bf8v*)&As[(wr * 64 + 16 * i + l15) * 32 + l4 * 8];
#pragma unroll
        for (int j = 0; j < 3; ++j)
            bg[j] = *(const bf8v*)&Bs[(wc * 48 + 16 * j + l15) * 32 + l4 * 8];
#pragma unroll
        for (int i = 0; i < 4; ++i)
#pragma unroll
            for (int j = 0; j < 3; ++j)
                acc[i][j] = __builtin_amdgcn_mfma_f32_16x16x32_bf16(
                    af[i], bg[j], acc[i][j], 0, 0, 0);
    }

#pragma unroll
    for (int j = 0; j < 3; ++j) {
        const int n = col0 + wc * 48 + 16 * j + l15;
        const int s = n / 768;            // block-uniform (96 | 768)
        const int rm = n - s * 768;
        const int h = rm >> 6, d = rm & 63;
        const float bv = bias[n];
        if (s == 2) {
#pragma unroll
            for (int i = 0; i < 4; ++i) {
                const int m = row0 + wr * 64 + 16 * i + l4 * 4;
                short4 pv;
                pv.x = (short)f2bf(acc[i][j][0] + bv);
                pv.y = (short)f2bf(acc[i][j][1] + bv);
                pv.z = (short)f2bf(acc[i][j][2] + bv);
                pv.w = (short)f2bf(acc[i][j][3] + bv);
                // blocked: [h][m>>4][d][m&15]; m&15 = l4*4 (short4-aligned)
                *(short4*)(vblk +
                           ((size_t)(h * 256 + (m >> 4)) * 64 + d) * 16 +
                           (m & 15)) = pv;
            }
        } else if (s == 0) {
#pragma unroll
            for (int i = 0; i < 4; ++i) {
                const int m = row0 + wr * 64 + 16 * i + l4 * 4;
#pragma unroll
                for (int r = 0; r < 4; ++r)
                    qbh[((size_t)h * NTOK + m + r) * 64 + d] =
                        (short)f2bf(acc[i][j][r] + bv);
            }
        } else {   // s == 1: K -> blocked fragment layout
#pragma unroll
            for (int i = 0; i < 4; ++i) {
                const int m = row0 + wr * 64 + 16 * i + l4 * 4;
                // m>>5 uniform across r (m&31 <= 28, r <= 3)
                short* dst = kblk +
                    ((((size_t)(h * 128 + (m >> 5)) * 8 + (d >> 3)) * 32 +
                      (m & 31)) * 8 + (d & 7));
#pragma unroll
                for (int r = 0; r < 4; ++r)
                    dst[r * 8] = (short)f2bf(acc[i][j][r] + bv);
            }
        }
    }
}

// ---------------------------------------------------------------------------
// Flash attention v17: v12 (verified 87us, absmax 4.9e-4) with EXACTLY ONE
// change: the vB load block moves ABOVE the S-MFMA cluster. No address, no
// arithmetic, no pragma, no launch change -- placement only. Mechanism: PV's
// vB wait gains the S-cluster as latency cover (~500cy vs ~300cy; L3 ~600-
// 900cy). Wait structure stays optimal: vB oldest at PV -> kf_next stays in
// flight. kf clamp restored to v12 form. Liveness audit ~130 regs < 170/wave
// cap at 3 waves/SIMD. Sentinels: WRITE_SIZE<=19.5MB, VGPR<=100 (spill);
// if WRITE >= 23MB the hoist spilled -> revert to v12 next round.
// ---------------------------------------------------------------------------
union FlashSMem {
    float relHs[64][65];   // 16640 B  [kh][q-local] (LOG2E-scaled), loop
    float U[128 * 65];     // 33280 B  prologue overlay
    struct {
        float OEp[64][64]; // 16384 B  epilogue O-combine (aliases relHs;
        float lEp[64];     //   256 B  safe: barrier after last rh read)
    };
};

__global__ __launch_bounds__(256, 3) void flash_mfma_kernel(
    const short* __restrict__ qbh, const short* __restrict__ kblk,
    const short* __restrict__ vblk, const float* __restrict__ rpw,
    const float* __restrict__ rph, short* __restrict__ aob)
{
    __shared__ __align__(16) FlashSMem sm;

    const int t = threadIdx.x;
    const int qt = blockIdx.x, head = blockIdx.y;
    const int row0 = qt * 64;
    const int lane = t & 63, w = t >> 6;
    const int qh2 = w & 1, th = w >> 1;
    const int l31 = lane & 31, hf = lane >> 5;
    const size_t hB = (size_t)head * NTOK * 64;
    const float SC = 0.125f * LOG2E;

    // Q as 32x32 B-fragments: B[k=d][n=q], lane n=l31, k = 8*hf + j
    const int q = row0 + qh2 * 32 + l31;
    bf8v bQ[4];
    {
        const short* qsrc = qbh + hB + (size_t)q * 64;
#pragma unroll
        for (int ks = 0; ks < 4; ++ks)
            bQ[ks] = *(const bf8v*)(qsrc + ks * 16 + hf * 8);
    }

    // blocked-K fragment base; prefetch it=0 now (L2 latency hides under
    // the relW/relH prologue).  addr(h,it,th,t32,ks) =
    //   h*262144 + (it*4+th*2+t32)*2048 + (ks*2+hf)*256 + l31*8   [shorts]
    const short* kb = kblk + (size_t)head * 262144 + th * 4096 + hf * 256 +
                      (size_t)l31 * 8;
    bf8v kf[2][4];
#pragma unroll
    for (int t32 = 0; t32 < 2; ++t32)
#pragma unroll
        for (int ks = 0; ks < 4; ++ks)
            kf[t32][ks] = *(const bf8v*)(kb + t32 * 2048 + ks * 512);

    // blocked-V fragment base
    const short* vb2 = vblk + ((size_t)head * 256 * 64 + l31) * 16 + hf * 8;

    // --- fused relW: U[j][qw] = sum_d rpw[j][d] Q[qw][d]; row j=127 never
    // gathered (qw+63-kw <= 126) -> clamp its load to row 0.
#pragma unroll
    for (int jt2 = 0; jt2 < 2; ++jt2) {
        const int jt = 2 * th + jt2;
        int j = jt * 32 + l31;
        if (j > 126) j = 0;
        const float* asrc = rpw + (size_t)j * 64;
        f16v c = {};
#pragma unroll
        for (int ks = 0; ks < 4; ++ks) {
            float4 u0 = *(const float4*)(asrc + ks * 16 + hf * 8);
            float4 u1 = *(const float4*)(asrc + ks * 16 + hf * 8 + 4);
            c = __builtin_amdgcn_mfma_f32_32x32x16_bf16(
                pack8(u0, u1), bQ[ks], c, 0, 0, 0);
        }
#pragma unroll
        for (int reg = 0; reg < 16; ++reg)
            sm.U[(jt * 32 + (reg & 3) + 8 * (reg >> 2) + 4 * hf) * 65 +
                 qh2 * 32 + l31] = c[reg];
    }
    __syncthreads();
    // gather relW into packed-bf16 registers (LOG2E-scaled) -- 16 VGPRs
    const int qw = qh2 * 32 + l31;
    uint2 rwp[2][4];
#pragma unroll
    for (int t32 = 0; t32 < 2; ++t32)
#pragma unroll
        for (int g = 0; g < 4; ++g) {
            const int kw = t32 * 32 + 8 * g + 4 * hf;
            const float v0 = sm.U[(qw + 63 - kw) * 65 + qw] * LOG2E;
            const float v1 = sm.U[(qw + 62 - kw) * 65 + qw] * LOG2E;
            const float v2 = sm.U[(qw + 61 - kw) * 65 + qw] * LOG2E;
            const float v3 = sm.U[(qw + 60 - kw) * 65 + qw] * LOG2E;
            rwp[t32][g].x = pkbf(v1, v0);
            rwp[t32][g].y = pkbf(v3, v2);
        }
    __syncthreads();   // U reads done before relHs overwrites

    // --- fused relH: relHs[kh][q] = LOG2E * (rph[qt+63-kh] . Q[q])
    {
        const int kh = th * 32 + l31;
        const float* asrc = rph + (size_t)(qt + 63 - kh) * 64;
        f16v c = {};
#pragma unroll
        for (int ks = 0; ks < 4; ++ks) {
            float4 u0 = *(const float4*)(asrc + ks * 16 + hf * 8);
            float4 u1 = *(const float4*)(asrc + ks * 16 + hf * 8 + 4);
            u0.x *= LOG2E; u0.y *= LOG2E; u0.z *= LOG2E; u0.w *= LOG2E;
            u1.x *= LOG2E; u1.y *= LOG2E; u1.z *= LOG2E; u1.w *= LOG2E;
            c = __builtin_amdgcn_mfma_f32_32x32x16_bf16(
                pack8(u0, u1), bQ[ks], c, 0, 0, 0);
        }
#pragma unroll
        for (int reg = 0; reg < 16; ++reg)
            sm.relHs[th * 32 + (reg & 3) + 8 * (reg >> 2) + 4 * hf]
                    [qh2 * 32 + l31] = c[reg];
    }
    __syncthreads();   // relHs visible to all waves; LAST barrier before loop

    f16v O[2] = {{}, {}};   // ntile: d = ntile*32+l31; rows q (C layout)
    float lsum = 0.f;

    for (int it = 0; it < 32; ++it) {
        // V frags HOISTED above S: issue now so PV's wait is covered by the
        // S cluster + softmax (~500cy) instead of softmax alone (~300cy).
        // vB stays oldest-outstanding at PV -> kf reload stays in flight.
        bf8v vB[2][2][2];   // [t32][ks2][nt]
        {
            const short* vit = vb2 + (size_t)(it * 8 + th * 4) * 1024;
#pragma unroll
            for (int t32 = 0; t32 < 2; ++t32)
#pragma unroll
                for (int ks2 = 0; ks2 < 2; ++ks2)
#pragma unroll
                    for (int nt = 0; nt < 2; ++nt)
                        vB[t32][ks2][nt] = *(const bf8v*)(
                            vit + ((size_t)(t32 * 2 + ks2) * 64 + nt * 32) *
                                      16);
        }

        // S^T: A = prefetched K frags (this wave's token half), B = bQ
        f16v acc[2] = {{}, {}};
#pragma unroll
        for (int ks = 0; ks < 4; ++ks)
#pragma unroll
            for (int t32 = 0; t32 < 2; ++t32)
                acc[t32] = __builtin_amdgcn_mfma_f32_32x32x16_bf16(
                    kf[t32][ks], bQ[ks], acc[t32], 0, 0, 0);

        // reload kf for it+1 into the SAME regs (WAR after last S MFMA);
        // has softmax+PV+next-S-issue to land.
        {
            const int itn = (it < 31) ? it + 1 : 31;
            const short* kp = kb + (size_t)itn * 8192;
#pragma unroll
            for (int t32 = 0; t32 < 2; ++t32)
#pragma unroll
                for (int ks = 0; ks < 4; ++ks)
                    kf[t32][ks] =
                        *(const bf8v*)(kp + t32 * 2048 + ks * 512);
        }

        const float rh = sm.relHs[2 * it + th][qw];

        // e = exp2(SC*acc + rw + rh); pack pairs via v_cvt_pk_bf16_f32
        unsigned xg[2][4], yg[2][4];
#pragma unroll
        for (int t32 = 0; t32 < 2; ++t32) {
            float sub = 0.f;
#pragma unroll
            for (int g = 0; g < 4; ++g) {
                const unsigned u0 = rwp[t32][g].x;
                const unsigned u1 = rwp[t32][g].y;
                const float b0 = __uint_as_float(u0 << 16) + rh;
                const float b1 = __uint_as_float(u0 & 0xffff0000u) + rh;
                const float b2 = __uint_as_float(u1 << 16) + rh;
                const float b3 = __uint_as_float(u1 & 0xffff0000u) + rh;
                const float e0 = __builtin_amdgcn_exp2f(
                    fmaf(acc[t32][4 * g + 0], SC, b0));
                const float e1 = __builtin_amdgcn_exp2f(
                    fmaf(acc[t32][4 * g + 1], SC, b1));
                const float e2 = __builtin_amdgcn_exp2f(
                    fmaf(acc[t32][4 * g + 2], SC, b2));
                const float e3 = __builtin_amdgcn_exp2f(
                    fmaf(acc[t32][4 * g + 3], SC, b3));
                sub += (e0 + e1) + (e2 + e3);
                xg[t32][g] = cvtpk(e0, e1);   // lo=e0, hi=e1
                yg[t32][g] = cvtpk(e2, e3);   // lo=e2, hi=e3
            }
            lsum += sub;
        }

        // PV: A-frag via permlane32_swap pairs; B = direct-loaded V frags
#pragma unroll
        for (int t32 = 0; t32 < 2; ++t32)
#pragma unroll
            for (int ks2 = 0; ks2 < 2; ++ks2) {
                auto px = __builtin_amdgcn_permlane32_swap(
                    xg[t32][2 * ks2], xg[t32][2 * ks2 + 1], false, false);
                auto py = __builtin_amdgcn_permlane32_swap(
                    yg[t32][2 * ks2], yg[t32][2 * ks2 + 1], false, false);
                int4 av;
                av.x = (int)px[0];
                av.y = (int)py[0];
                av.z = (int)px[1];
                av.w = (int)py[1];
                union { int4 i; bf8v v; } u; u.i = av;
#pragma unroll
                for (int nt = 0; nt < 2; ++nt)
                    O[nt] = __builtin_amdgcn_mfma_f32_32x32x16_bf16(
                        u.v, vB[t32][ks2][nt], O[nt], 0, 0, 0);
            }
    }

    // epilogue: lanes l / l+32 share q -> reduce; then combine the two
    // token-half waves (th) via LDS union members, normalize, store.
    lsum += __shfl_xor(lsum, 32);
    __syncthreads();   // all waves past their last relHs read -> OEp may alias
    if (th == 1) {
#pragma unroll
        for (int nt = 0; nt < 2; ++nt)
#pragma unroll
            for (int reg = 0; reg < 16; ++reg) {
                const int qr = (reg & 3) + 8 * (reg >> 2) + 4 * hf;
                sm.OEp[qh2 * 32 + qr][nt * 32 + l31] = O[nt][reg];
            }
        if (lane < 32) sm.lEp[qh2 * 32 + l31] = lsum;
    }
    __syncthreads();
    if (th == 0) {
        lsum += sm.lEp[qh2 * 32 + l31];
        const float linv = 1.0f / lsum;
#pragma unroll
        for (int nt = 0; nt < 2; ++nt)
#pragma unroll
            for (int reg = 0; reg < 16; ++reg) {
                const int qr = (reg & 3) + 8 * (reg >> 2) + 4 * hf;
                const float li = __shfl(linv, qr);
                const float o =
                    O[nt][reg] + sm.OEp[qh2 * 32 + qr][nt * 32 + l31];
                aob[(size_t)(row0 + qh2 * 32 + qr) * 768 + head * 64 +
                    nt * 32 + l31] = (short)f2bf(o * li);
            }
    }
}

// ---------------------------------------------------------------------------
// proj GEMM (MFMA bf16), 64x64 tile -> grid (12,64)=768 blocks (3 blocks/CU).
// ---------------------------------------------------------------------------
__global__ __launch_bounds__(256) void proj_mfma_kernel(
    const short* __restrict__ aoh, const short* __restrict__ pwT,
    const float* __restrict__ bias, float* __restrict__ out)
{
    __shared__ __align__(16) short As[64 * 32];
    __shared__ __align__(16) short Bs[64 * 32];
    const int t = threadIdx.x;
    const int w = t >> 6, lane = t & 63;
    const int l15 = lane & 15, l4 = lane >> 4;
    const int wr = w >> 1, wc = w & 1;
    const int row0 = blockIdx.y * 64, col0 = blockIdx.x * 64;
    const int ldr = lane >> 2;
    const int ldk = (lane & 3) * 8;

    f4v acc[2][2] = {};
    const short* aBase = aoh + (size_t)(row0 + w * 16 + ldr) * 768 + ldk;
    const short* bBase = pwT + (size_t)(col0 + w * 16 + ldr) * 768 + ldk;

    for (int kk = 0; kk < 768; kk += 32) {
        __syncthreads();
        gload_lds16(aBase + kk, &As[(w * 16) * 32]);
        gload_lds16(bBase + kk, &Bs[(w * 16) * 32]);
        __syncthreads();
        bf8v af[2], bg[2];
#pragma unroll
        for (int i = 0; i < 2; ++i)
            af[i] = *(const bf8v*)&As[(wr * 32 + 16 * i + l15) * 32 + l4 * 8];
#pragma unroll
        for (int j = 0; j < 2; ++j)
            bg[j] = *(const bf8v*)&Bs[(wc * 32 + 16 * j + l15) * 32 + l4 * 8];
#pragma unroll
        for (int i = 0; i < 2; ++i)
#pragma unroll
            for (int j = 0; j < 2; ++j)
                acc[i][j] = __builtin_amdgcn_mfma_f32_16x16x32_bf16(
                    af[i], bg[j], acc[i][j], 0, 0, 0);
    }

#pragma unroll
    for (int j = 0; j < 2; ++j) {
        const int n = col0 + wc * 32 + 16 * j + l15;
        const float bv = bias[n];
#pragma unroll
        for (int i = 0; i < 2; ++i) {
            const int m = row0 + wr * 32 + 16 * i + l4 * 4;
#pragma unroll
            for (int r = 0; r < 4; ++r)
                out[(size_t)(m + r) * 768 + n] = acc[i][j][r] + bv;
        }
    }
}

// ---------------------------------------------------------------------------
extern "C" void kernel_launch(void* const* d_in, const int* in_sizes, int n_in,
                              void* d_out, int out_size, void* d_ws,
                              size_t ws_size, hipStream_t stream)
{
    (void)in_sizes; (void)n_in; (void)out_size; (void)ws_size;
    const float* x    = (const float*)d_in[0];
    const float* qkvw = (const float*)d_in[1];
    const float* qkvb = (const float*)d_in[2];
    const float* pw   = (const float*)d_in[3];
    const float* pb   = (const float*)d_in[4];
    const float* rph  = (const float*)d_in[5];
    const float* rpw  = (const float*)d_in[6];
    float* out = (float*)d_out;

    const size_t S = (size_t)NHEADS * NTOK * 64;  // 3,145,728 (= 4096*768)
    short* qbh  = (short*)d_ws;          // S bf16   q  [h][tok][d]
    short* kblk = qbh + S;               // S bf16   k  [h][tok/32][d/8][tok%32][d%8]
    short* vblk = kblk + S;              // S bf16   v  [h][tok/16][d][tok%16]
    short* xh   = vblk + S;              // S bf16   x [tok][c]; dead after
    short* aob  = xh;                    //   qkv -> aliased as attn out
    short* wqkvT = xh + S;               // 2304*768 bf16
    short* pwT  = wqkvT + (size_t)2304 * 768;  // 768*768 bf16
    // total ~29.6 MB

    prep_kernel<<<dim3(2112), 256, 0, stream>>>(x, qkvw, pw, xh, wqkvT, pwT);
    qkv_mfma_kernel<<<dim3(24, 32), 256, 0, stream>>>(xh, wqkvT, qkvb,
                                                      qbh, kblk, vblk);
    flash_mfma_kernel<<<dim3(64, NHEADS), 256, 0, stream>>>(qbh, kblk, vblk,
                                                            rpw, rph, aob);
    proj_mfma_kernel<<<dim3(12, 64), 256, 0, stream>>>(aob, pwT, pb, out);
}